// Round 7
// baseline (211.072 us; speedup 1.0000x reference)
//
#include <hip/hip_runtime.h>
#include <math.h>

// GCN 2-layer, N=100K, E=3.2M, feat 1->16->2, log_softmax.
//
// R6 lesson: tile-local CSR (rowOff) pushed a 512-wide scan + uncoalesced
// rowOff gather + 40KB table build into EVERY aggregation block x3 kernels.
// R7: counting sort to a GLOBALLY bucket-contiguous payload:
//   hist (dst only) -> scan -> place (per-(tile,bucket) run reservation via
//   one global u32 atomicAdd; edges written straight to final slots — runs
//   are ~336 B and written within a few waves, so XCD L2 write-back
//   assembles nearly-full lines, unlike R4's bucket-wide random scatter).
// Aggregation kernels then stream start[b]..start[b+1] coalesced with ZERO
// metadata: per edge = payload load + node gather + LDS atomic.
// Algebra: layer1 rank-1 (scalar s per node); 2-class log_softmax needs only
// d = a1-a0 (scalar gd per node); dinv[dst] factored into epilogues.

static constexpr int BS        = 512;    // block size everywhere
static constexpr int CHUNK     = 256;    // nodes per bucket (pow2)
static constexpr int LOG_CHUNK = 8;
static constexpr int MAXNB     = 512;    // max buckets (N <= 131072); == BS
static constexpr int EPT_H     = 8192;   // edges per hist tile
static constexpr int EPT_P     = 16384;  // edges per place tile (runs ~42 edges)

// ======================= sort phase =======================

__global__ __launch_bounds__(BS) void zero_cnt_kernel(unsigned int* __restrict__ cnt,
                                                      int nb) {
    int t = threadIdx.x;
    if (t < nb) cnt[t] = 0u;
}

__global__ __launch_bounds__(BS) void hist_kernel(const int* __restrict__ dst,
                                                  unsigned int* __restrict__ cnt,
                                                  int E, int nb) {
    __shared__ unsigned int h[MAXNB];
    const int t = threadIdx.x;
    for (int i = t; i < nb; i += BS) h[i] = 0u;
    __syncthreads();
    const int base = blockIdx.x * EPT_H;
    const int nE   = min(EPT_H, E - base);
    for (int k = t; k < nE; k += BS)
        atomicAdd(&h[(unsigned int)dst[base + k] >> LOG_CHUNK], 1u);
    __syncthreads();
    for (int i = t; i < nb; i += BS) {
        unsigned int c = h[i];
        if (c) atomicAdd(&cnt[i], c);
    }
}

__global__ __launch_bounds__(BS) void scan_kernel(const unsigned int* __restrict__ cnt,
                                                  unsigned int* __restrict__ start,   // nb+1
                                                  unsigned int* __restrict__ cursor,  // nb
                                                  int nb) {
    __shared__ unsigned int s[MAXNB];
    const int t = threadIdx.x;
    unsigned int c = (t < nb) ? cnt[t] : 0u;
    s[t] = c;
    __syncthreads();
    for (int off = 1; off < MAXNB; off <<= 1) {
        unsigned int v = (t >= off) ? s[t - off] : 0u;
        __syncthreads();
        s[t] += v;
        __syncthreads();
    }
    if (t < nb) { start[t + 1] = s[t]; cursor[t] = s[t] - c; }
    if (t == 0) start[0] = 0u;
}

__global__ __launch_bounds__(BS) void place_kernel(
    const int* __restrict__ src, const int* __restrict__ dst,
    const float* __restrict__ w,
    unsigned int* __restrict__ cursor,           // [nb] global bump cursors
    unsigned long long* __restrict__ payload,    // [E] bucket-contiguous
    int E, int nb) {
    __shared__ unsigned int h[MAXNB];
    __shared__ unsigned int lcur[MAXNB];         // global slot cursors per bucket
    const int base = blockIdx.x * EPT_P;
    const int nE   = min(EPT_P, E - base);
    const int t    = threadIdx.x;
    for (int i = t; i < nb; i += BS) h[i] = 0u;
    __syncthreads();
    int dc[EPT_P / BS];                          // per-thread dst cache (32 regs)
    int cnt_ = 0;
    for (int k = t; k < nE; k += BS) {
        int d = dst[base + k];
        dc[cnt_++] = d;
        atomicAdd(&h[(unsigned int)d >> LOG_CHUNK], 1u);
    }
    __syncthreads();
    // one global reservation per (tile,bucket): run base in final payload
    for (int i = t; i < nb; i += BS) {
        unsigned int c = h[i];
        lcur[i] = c ? atomicAdd(&cursor[i], c) : 0u;
    }
    __syncthreads();
    cnt_ = 0;
    for (int k = t; k < nE; k += BS) {
        int e = base + k;
        int d = dc[cnt_++];
        int b = (unsigned int)d >> LOG_CHUNK;
        unsigned int slot = atomicAdd(&lcur[b], 1u);     // LDS atomic -> global slot
        unsigned long long p =
            ((unsigned long long)__float_as_uint(w[e]) << 32) |
            ((unsigned int)src[e] << LOG_CHUNK) |
            (unsigned int)(d & (CHUNK - 1));
        payload[slot] = p;      // random only within this tile's ~336 B runs
    }
}

// ======================= aggregation phase (no metadata) =======================

__global__ __launch_bounds__(BS) void deg_dinv_kernel(
    const unsigned long long* __restrict__ payload,
    const unsigned int* __restrict__ start,
    const float* __restrict__ x,
    float* __restrict__ dinv, float* __restrict__ xd, int N) {
    __shared__ float acc[CHUNK];
    const int b = blockIdx.x, t = threadIdx.x;
    if (t < CHUNK) acc[t] = 0.0f;
    __syncthreads();
    const unsigned int s0 = start[b], s1 = start[b + 1];
    for (unsigned int i = s0 + t; i < s1; i += BS) {
        unsigned long long p = payload[i];
        atomicAdd(&acc[(unsigned int)p & (CHUNK - 1)],
                  __uint_as_float((unsigned int)(p >> 32)));
    }
    __syncthreads();
    int n = b * CHUNK + t;
    if (t < CHUNK && n < N) {
        float d = acc[t] + 1.0f;                 // self-loop fill 1.0
        float r = (d > 0.0f) ? rsqrtf(d) : 0.0f;
        dinv[n] = r;
        xd[n]   = r * x[n];
    }
}

__global__ __launch_bounds__(BS) void s_gamma_kernel(
    const unsigned long long* __restrict__ payload,
    const unsigned int* __restrict__ start,
    const float* __restrict__ dinv,
    const float* __restrict__ xd,
    const float* __restrict__ W1,    // [16]
    const float* __restrict__ b1,    // [16]
    const float* __restrict__ W2,    // [16][2]
    float* __restrict__ gd, int N) {
    __shared__ float acc[CHUNK];
    const int b = blockIdx.x, t = threadIdx.x;
    if (t < CHUNK) acc[t] = 0.0f;
    __syncthreads();
    const unsigned int s0 = start[b], s1 = start[b + 1];
    for (unsigned int i = s0 + t; i < s1; i += BS) {
        unsigned long long p = payload[i];
        float wv = __uint_as_float((unsigned int)(p >> 32));
        unsigned int lo32 = (unsigned int)p;
        atomicAdd(&acc[lo32 & (CHUNK - 1)], wv * xd[lo32 >> LOG_CHUNK]);
    }
    __syncthreads();
    int n = b * CHUNK + t;
    if (t < CHUNK && n < N) {
        float dv = dinv[n];
        float sv = dv * (acc[t] + xd[n]);        // + self-loop dv*dv*x[n]
        float g = 0.0f;
#pragma unroll
        for (int f = 0; f < 16; ++f) {
            float h = fmaxf(sv * W1[f] + b1[f], 0.0f);     // relu(layer1)
            g += h * (W2[2 * f + 1] - W2[2 * f + 0]);      // gamma = g1-g0
        }
        gd[n] = dv * g;                          // pre-scaled for layer 2
    }
}

__global__ __launch_bounds__(BS) void d_out_kernel(
    const unsigned long long* __restrict__ payload,
    const unsigned int* __restrict__ start,
    const float* __restrict__ dinv,
    const float* __restrict__ gd,
    const float* __restrict__ b2,    // [2]
    float* __restrict__ out, int N) {
    __shared__ float acc[CHUNK];
    const int b = blockIdx.x, t = threadIdx.x;
    if (t < CHUNK) acc[t] = 0.0f;
    __syncthreads();
    const unsigned int s0 = start[b], s1 = start[b + 1];
    for (unsigned int i = s0 + t; i < s1; i += BS) {
        unsigned long long p = payload[i];
        float wv = __uint_as_float((unsigned int)(p >> 32));
        unsigned int lo32 = (unsigned int)p;
        atomicAdd(&acc[lo32 & (CHUNK - 1)], wv * gd[lo32 >> LOG_CHUNK]);
    }
    __syncthreads();
    int n = b * CHUNK + t;
    if (t < CHUNK && n < N) {
        float dv = dinv[n];
        float d = dv * (acc[t] + gd[n]) + (b2[1] - b2[0]);
        float lse = fmaxf(d, 0.0f) + log1pf(expf(-fabsf(d)));   // log(1+e^d)
        out[2 * n + 0] = -lse;
        out[2 * n + 1] = d - lse;
    }
}

// ======================= fallback: R3 global-atomic path =======================

static constexpr int BLOCK = 256;

__global__ void zero_kernel(float* __restrict__ a, float* __restrict__ b, int n2) {
    int i = blockIdx.x * blockDim.x + threadIdx.x;
    if (i < n2) { a[i] = 0.0f; b[i] = 0.0f; }
}
__global__ void deg_kernel(const int* __restrict__ dst, const float* __restrict__ w,
                           float* __restrict__ deg, int E) {
    int e = blockIdx.x * blockDim.x + threadIdx.x;
    if (e < E) atomicAdd(&deg[dst[e]], w[e]);
}
__global__ void dinv_kernel(float* __restrict__ deg, int N) {
    int n = blockIdx.x * blockDim.x + threadIdx.x;
    if (n < N) {
        float d = deg[n] + 1.0f;
        deg[n] = (d > 0.0f) ? rsqrtf(d) : 0.0f;
    }
}
__global__ void s_kernel(const int* __restrict__ src, const int* __restrict__ dst,
                         const float* __restrict__ w, const float* __restrict__ dinv,
                         const float* __restrict__ x, float* __restrict__ s, int E) {
    int e = blockIdx.x * blockDim.x + threadIdx.x;
    if (e < E) {
        int si = src[e], di = dst[e];
        atomicAdd(&s[di], dinv[si] * w[e] * dinv[di] * x[si]);
    }
}
__global__ void g_kernel(const float* __restrict__ s, const float* __restrict__ dinv,
                         const float* __restrict__ x, const float* __restrict__ W1,
                         const float* __restrict__ b1, const float* __restrict__ W2,
                         float2* __restrict__ g, int N) {
    int n = blockIdx.x * blockDim.x + threadIdx.x;
    if (n < N) {
        float dv = dinv[n];
        float sv = s[n] + dv * dv * x[n];
        float g0 = 0.0f, g1 = 0.0f;
#pragma unroll
        for (int f = 0; f < 16; ++f) {
            float h = fmaxf(sv * W1[f] + b1[f], 0.0f);
            g0 += h * W2[2 * f + 0];
            g1 += h * W2[2 * f + 1];
        }
        g[n] = make_float2(g0, g1);
    }
}
__global__ void agg2_kernel(const int* __restrict__ src, const int* __restrict__ dst,
                            const float* __restrict__ w, const float* __restrict__ dinv,
                            const float2* __restrict__ g, float* __restrict__ agg, int E) {
    int e = blockIdx.x * blockDim.x + threadIdx.x;
    if (e < E) {
        int si = src[e], di = dst[e];
        float norm = dinv[si] * w[e] * dinv[di];
        float2 gv = g[si];
        atomicAdd(&agg[2 * di + 0], norm * gv.x);
        atomicAdd(&agg[2 * di + 1], norm * gv.y);
    }
}
__global__ void out_kernel(float* __restrict__ out, const float* __restrict__ dinv,
                           const float2* __restrict__ g, const float* __restrict__ b2, int N) {
    int n = blockIdx.x * blockDim.x + threadIdx.x;
    if (n < N) {
        float dv2 = dinv[n] * dinv[n];
        float2 gv = g[n];
        float a0 = out[2 * n + 0] + dv2 * gv.x + b2[0];
        float a1 = out[2 * n + 1] + dv2 * gv.y + b2[1];
        float m = fmaxf(a0, a1);
        float lse = m + logf(expf(a0 - m) + expf(a1 - m));
        out[2 * n + 0] = a0 - lse;
        out[2 * n + 1] = a1 - lse;
    }
}

// ======================= launch =======================

extern "C" void kernel_launch(void* const* d_in, const int* in_sizes, int n_in,
                              void* d_out, int out_size, void* d_ws, size_t ws_size,
                              hipStream_t stream) {
    const float* x  = (const float*)d_in[0];
    const int*   ei = (const int*)d_in[1];     // [2, E] delivered as int32
    const float* w  = (const float*)d_in[2];
    const float* W1 = (const float*)d_in[3];
    const float* b1 = (const float*)d_in[4];
    const float* W2 = (const float*)d_in[5];
    const float* b2 = (const float*)d_in[6];
    float* out = (float*)d_out;

    const int N = in_sizes[0];
    const int E = in_sizes[2];
    const int* src = ei;
    const int* dst = ei + E;

    const int nb = (N + CHUNK - 1) / CHUNK;    // 391

    // ws layout: payload | cnt | start | cursor | dinv | xd | gd
    size_t off = 0;
    size_t payload_off = off;  off += (size_t)E * 8;
    size_t cnt_off     = off;  off += (size_t)nb * 4;
    size_t start_off   = off;  off += (size_t)(nb + 1) * 4;
    size_t cursor_off  = off;  off += (size_t)nb * 4;
    off = (off + 7) & ~(size_t)7;
    size_t dinv_off    = off;  off += (size_t)N * 4;
    size_t xd_off      = off;  off += (size_t)N * 4;
    size_t gd_off      = off;  off += (size_t)N * 4;
    const size_t required = off;

    if (nb <= MAXNB && ws_size >= required) {
        char* wsb = (char*)d_ws;
        unsigned long long* payload = (unsigned long long*)(wsb + payload_off);
        unsigned int* cnt    = (unsigned int*)(wsb + cnt_off);
        unsigned int* startp = (unsigned int*)(wsb + start_off);
        unsigned int* cursor = (unsigned int*)(wsb + cursor_off);
        float* dinv = (float*)(wsb + dinv_off);
        float* xd   = (float*)(wsb + xd_off);
        float* gd   = (float*)(wsb + gd_off);

        const int gridH = (E + EPT_H - 1) / EPT_H;   // 391
        const int gridP = (E + EPT_P - 1) / EPT_P;   // 196

        zero_cnt_kernel<<<1,     BS, 0, stream>>>(cnt, nb);
        hist_kernel    <<<gridH, BS, 0, stream>>>(dst, cnt, E, nb);
        scan_kernel    <<<1,     BS, 0, stream>>>(cnt, startp, cursor, nb);
        place_kernel   <<<gridP, BS, 0, stream>>>(src, dst, w, cursor, payload, E, nb);
        deg_dinv_kernel<<<nb,    BS, 0, stream>>>(payload, startp, x, dinv, xd, N);
        s_gamma_kernel <<<nb,    BS, 0, stream>>>(payload, startp, dinv, xd, W1, b1, W2, gd, N);
        d_out_kernel   <<<nb,    BS, 0, stream>>>(payload, startp, dinv, gd, b2, out, N);
    } else {
        // R3 fallback: global-atomic path (needs 4N floats of ws)
        float*  ws   = (float*)d_ws;
        float*  dinv = ws;
        float*  s    = ws + (size_t)N;
        float2* g    = (float2*)(ws + (size_t)2 * N);
        const int gridE  = (E + BLOCK - 1) / BLOCK;
        const int gridN  = (N + BLOCK - 1) / BLOCK;
        const int gridN2 = (2 * N + BLOCK - 1) / BLOCK;
        zero_kernel<<<gridN2, BLOCK, 0, stream>>>(ws, out, 2 * N);
        deg_kernel <<<gridE,  BLOCK, 0, stream>>>(dst, w, dinv, E);
        dinv_kernel<<<gridN,  BLOCK, 0, stream>>>(dinv, N);
        s_kernel   <<<gridE,  BLOCK, 0, stream>>>(src, dst, w, dinv, x, s, E);
        g_kernel   <<<gridN,  BLOCK, 0, stream>>>(s, dinv, x, W1, b1, W2, g, N);
        agg2_kernel<<<gridE,  BLOCK, 0, stream>>>(src, dst, w, dinv, g, out, E);
        out_kernel <<<gridN,  BLOCK, 0, stream>>>(out, dinv, g, b2, N);
    }
}